// Round 4
// baseline (118.875 us; speedup 1.0000x reference)
//
#include <hip/hip_runtime.h>
#include <hip/hip_bf16.h>

// SparseDynamicConv3d: out[n,o] = sum_k sum_c feat[idx[k,n],c] * W[k,c,o]
// Round 9 (re-run; previous attempt hit an infra container failure, no data):
// M=64 rows/wave (two 32-row acc groups sharing each B fragment) on the
// round-6 LDS pipeline. 782 blocks x 128 threads (2 waves): per-CU LDS b128
// ops drop ~40% (each 6KB B(k) read now feeds 64 rows, not 32). Round 7
// proved M=64 numerically; its loss was the missing LDS pipeline + bare-
// global B, not the tiling. Occupancy is grid-limited (~6 waves/CU) so the
// fp32 deferred-cvt F-ring (96 VGPR) is free; launch_bounds(128,2) caps
// VGPR at 256 so both blocks stay co-resident per CU.
#define NVOX       100000
#define INC        48
#define INC_MAX    64
#define OUTC       64
#define OUTC_MAX   96
#define KOFF       27
#define WTB_K      3072                      // shorts per k: 48x64, frag-packed
#define WTB_ELEMS  (KOFF * WTB_K)            // 82944
#define ZROW_FLOATS 48
#define WS_NEED    ((size_t)WTB_ELEMS * 2 + ZROW_FLOATS * 4)   // 166080 B
#define WTB_PREP_BLKS  (WTB_ELEMS / 256)     // 324 exact
#define MAIN_BLOCKS 782                      // 1564 waves of 64 rows (1563 used)

typedef __attribute__((ext_vector_type(8)))  short short8;
typedef __attribute__((ext_vector_type(4)))  float floatx4;
typedef __attribute__((ext_vector_type(16))) float floatx16;

__device__ __forceinline__ short f2bf(float f) {
    union { __hip_bfloat16 h; short s; } u;
    u.h = __float2bfloat16(f);
    return u.s;
}

// wtb: frag-packed per k as 384 16B chunks: chunk = (ks*2+nt)*64 + lane,
//      element j: B[c = ks*16 + (lane>>5)*8 + j][o = nt*32 + (lane&31)]
//      (32x32x16 B-operand layout, verified rounds 1-6).
// zrowf: 48 zero floats — gather target for idx<0 lanes.
__global__ void __launch_bounds__(256)
prep_w(const float* __restrict__ wk, short* __restrict__ wtb,
       float* __restrict__ zrowf)
{
    int b = blockIdx.x;
    if (b < WTB_PREP_BLKS) {
        int t = b * 256 + threadIdx.x;       // < 82944 exact
        int k = t / WTB_K, r = t % WTB_K;
        int chunk = r >> 3, j = r & 7;
        int f = chunk >> 6, lane = chunk & 63;
        int ks = f >> 1, nt = f & 1;
        int c = ks * 16 + (lane >> 5) * 8 + j;      // 0..47, K=48 exact
        int o = nt * 32 + (lane & 31);
        wtb[t] = f2bf(wk[k * (INC_MAX * OUTC_MAX) + c * OUTC_MAX + o]);
    } else if (threadIdx.x < ZROW_FLOATS) {
        zrowf[threadIdx.x] = 0.f;
    }
}

__global__ void __launch_bounds__(128, 2)
spconv_main(const float* __restrict__ feat, const short* __restrict__ wtb,
            const float* __restrict__ zrowf, const int* __restrict__ idx,
            float* __restrict__ out)
{
    __shared__ short Bs[4][WTB_K];   // 4 x 6KB single-k B buffers

    const int tid  = threadIdx.x;
    const int lane = tid & 63;
    const int wave = tid >> 6;
    const int l32  = lane & 31;
    const int hi   = lane >> 5;      // 0/1: which 8-channel half this lane holds

    // XCD-contiguous swizzle (bijective for bid<776, identity tail)
    int bid = blockIdx.x;
    int sb  = (bid < 776) ? ((bid & 7) * 97 + (bid >> 3)) : bid;

    const int m0   = (sb * 2 + wave) * 64;     // 64 rows per wave, 2 groups of 32
    const bool act  = (m0 < NVOX);             // group-0 validity (NVOX%32==0)
    const bool act1 = (m0 + 32 < NVOX);        // group-1 validity
    const int rr0  = act  ? (m0 + l32)      : 0;
    const int rr1  = act1 ? (m0 + 32 + l32) : 0;

    floatx16 acc[2][2];                        // [group][nt]
    #pragma unroll
    for (int g = 0; g < 2; ++g)
        #pragma unroll
        for (int nt = 0; nt < 2; ++nt)
            #pragma unroll
            for (int r = 0; r < 16; ++r) acc[g][nt][r] = 0.f;

    floatx4 F[2][2][3][2]; // [k&1][group][ks][half] fp32 A rows (cvt deferred)
    short8  bst[2][3];     // [k&1][plane] B-stage ring (1024 shorts/plane)
    int     rowg[4][2];    // [k&3][group] gathered row (<0 -> zrowf)
    bool    va4[4];        // [k&3] wave-level tap validity (set at ldrow)
    bool    ca[2];         // [k&1] compute guard (captured at aload; va4[k&3]
                           // is clobbered by ldrow(k+4) before compute(k))

    auto ldrow = [&](int k) {
        int t0 = idx[k * NVOX + rr0];
        int t1 = act1 ? idx[k * NVOX + rr1] : -1;
        rowg[k & 3][0] = t0;
        rowg[k & 3][1] = t1;
        va4[k & 3] = __any((t0 >= 0) || (t1 >= 0));
    };
    auto aload = [&](int k) {
        bool v = va4[k & 3];
        ca[k & 1] = v;
        if (v) {
            #pragma unroll
            for (int g = 0; g < 2; ++g) {
                int t = rowg[k & 3][g];
                const float* p = (t >= 0) ? (feat + (size_t)t * INC) : zrowf;
                #pragma unroll
                for (int ks = 0; ks < 3; ++ks) {
                    const floatx4* q = (const floatx4*)(p + ks * 16 + hi * 8);
                    F[k & 1][g][ks][0] = q[0];
                    F[k & 1][g][ks][1] = q[1];
                }
            }
        }
    };
    auto bload = [&](int k) {
        #pragma unroll
        for (int p = 0; p < 3; ++p)
            bst[k & 1][p] = *(const short8*)(wtb + k * WTB_K + p * 1024 + tid * 8);
    };
    auto compute = [&](int k) {
        if (!ca[k & 1]) return;
        #pragma unroll
        for (int ks = 0; ks < 3; ++ks) {
            short8 b0 = *(const short8*)&Bs[k & 3][(ks * 128 + lane) * 8];
            short8 b1 = *(const short8*)&Bs[k & 3][(ks * 128 + 64 + lane) * 8];
            short8 a0, a1;
            #pragma unroll
            for (int j = 0; j < 4; ++j) {
                a0[j]     = f2bf(F[k & 1][0][ks][0][j]);
                a0[4 + j] = f2bf(F[k & 1][0][ks][1][j]);
                a1[j]     = f2bf(F[k & 1][1][ks][0][j]);
                a1[4 + j] = f2bf(F[k & 1][1][ks][1][j]);
            }
            acc[0][0] = __builtin_amdgcn_mfma_f32_32x32x16_bf16(a0, b0, acc[0][0], 0, 0, 0);
            acc[0][1] = __builtin_amdgcn_mfma_f32_32x32x16_bf16(a0, b1, acc[0][1], 0, 0, 0);
            acc[1][0] = __builtin_amdgcn_mfma_f32_32x32x16_bf16(a1, b0, acc[1][0], 0, 0, 0);
            acc[1][1] = __builtin_amdgcn_mfma_f32_32x32x16_bf16(a1, b1, acc[1][1], 0, 0, 0);
        }
    };

    // ---- prologue ----
    ldrow(0); ldrow(1); ldrow(2); ldrow(3);
    bload(0); bload(1);
    aload(0); aload(1);

    #pragma unroll
    for (int j = 0; j < 14; ++j) {
        const int kk = 2 * j;

        // commit staged B(kk), B(kk+1) regs to LDS buffers kk&3, (kk+1)&3
        #pragma unroll
        for (int p = 0; p < 3; ++p)
            *(short8*)&Bs[kk & 3][p * 1024 + tid * 8] = bst[0][p];
        if (kk + 1 < KOFF) {
            #pragma unroll
            for (int p = 0; p < 3; ++p)
                *(short8*)&Bs[(kk + 1) & 3][p * 1024 + tid * 8] = bst[1][p];
        }
        __syncthreads();

        // stage next pair's B into regs; idx two pairs ahead
        if (kk + 2 < KOFF) bload(kk + 2);
        if (kk + 3 < KOFF) bload(kk + 3);
        if (kk + 4 < KOFF) ldrow(kk + 4);
        if (kk + 5 < KOFF) ldrow(kk + 5);

        compute(kk);
        if (kk + 2 < KOFF) aload(kk + 2);     // refills F[kk&1] after use
        if (kk + 1 < KOFF) {
            compute(kk + 1);
            if (kk + 3 < KOFF) aload(kk + 3);
        }
    }

    // ---- epilogue: D col = nt*32 + (lane&31), row = (r&3) + 8*(r>>2) + 4*hi ----
    if (act) {
        #pragma unroll
        for (int nt = 0; nt < 2; ++nt) {
            #pragma unroll
            for (int r = 0; r < 16; ++r) {
                int row = (r & 3) + 8 * (r >> 2) + 4 * hi;
                out[(m0 + row) * OUTC + nt * 32 + l32] = acc[0][nt][r];
            }
        }
    }
    if (act1) {
        #pragma unroll
        for (int nt = 0; nt < 2; ++nt) {
            #pragma unroll
            for (int r = 0; r < 16; ++r) {
                int row = (r & 3) + 8 * (r >> 2) + 4 * hi;
                out[(m0 + 32 + row) * OUTC + nt * 32 + l32] = acc[1][nt][r];
            }
        }
    }
}

// Safety fallback (only if workspace were too small): plain fp32.
__global__ void __launch_bounds__(256)
spconv_fallback(const float* __restrict__ feat, const float* __restrict__ wk,
                const int* __restrict__ idx, float* __restrict__ out)
{
    int t = blockIdx.x * 256 + threadIdx.x;
    if (t >= NVOX * OUTC) return;
    int n = t >> 6, o = t & 63;
    float s = 0.f;
    for (int k = 0; k < KOFF; ++k) {
        int g = idx[k * NVOX + n];
        if (g >= 0) {
            const float* fr = feat + g * INC;
            const float* wr = wk + k * (INC_MAX * OUTC_MAX) + o;
            #pragma unroll 8
            for (int c = 0; c < INC; ++c) s += fr[c] * wr[c * OUTC_MAX];
        }
    }
    out[t] = s;
}

extern "C" void kernel_launch(void* const* d_in, const int* in_sizes, int n_in,
                              void* d_out, int out_size, void* d_ws, size_t ws_size,
                              hipStream_t stream) {
    const float* feat = (const float*)d_in[0];
    const float* wk   = (const float*)d_in[1];
    const int*   idx  = (const int*)d_in[2];
    float* out = (float*)d_out;

    if (ws_size >= WS_NEED) {
        short* wtb   = (short*)d_ws;
        float* zrowf = (float*)((char*)d_ws + (size_t)WTB_ELEMS * 2);
        prep_w<<<WTB_PREP_BLKS + 1, 256, 0, stream>>>(wk, wtb, zrowf);
        spconv_main<<<MAIN_BLOCKS, 128, 0, stream>>>(feat, wtb, zrowf, idx, out);
    } else {
        spconv_fallback<<<(NVOX * OUTC + 255) / 256, 256, 0, stream>>>(feat, wk, idx, out);
    }
}

// Round 5
// 108.083 us; speedup vs baseline: 1.0999x; 1.0999x over previous
//
#include <hip/hip_runtime.h>
#include <hip/hip_bf16.h>

// SparseDynamicConv3d: out[n,o] = sum_k sum_c feat[idx[k,n],c] * W[k,c,o]
// Round 10: revert to the measured-best round-6 structure (109.3 us total:
// M=32/wave, 256 thr, 12 waves/CU, bf16 featb + LDS B pipeline). Rounds 7/9
// proved M=64 (6 waves/CU) is latency-bound regardless of B path. Single
// change vs round 6: wave-uniform tap skip (proven numerically in round 8)
// — grid is 4.77% occupied so ~21% of wave-taps have no valid row; skip
// their 6 ds_read_b128 + 6 MFMA + 3 A-gathers. B staging + barriers stay
// unconditional -> LDS schedule identical, race-free.
#define NVOX       100000
#define INC        48
#define INC_MAX    64
#define OUTC       64
#define OUTC_MAX   96
#define KOFF       27
#define FEAT_ROW   64                        // bf16 row padded to 128 B
#define FEATB_ELEMS ((NVOX + 1) * FEAT_ROW)  // +1 zero row for idx<0
#define WTB_K      3072                      // shorts per k: 48x64, frag-packed
#define WTB_ELEMS  (KOFF * WTB_K)            // 82944
#define WS_NEED    ((size_t)(FEATB_ELEMS + WTB_ELEMS) * 2)
#define FEAT_THREADS ((NVOX + 1) * 8)        // 800008
#define FEAT_PREP_BLKS ((FEAT_THREADS + 255) / 256)   // 3126
#define WTB_PREP_BLKS  (WTB_ELEMS / 256)     // 324 exact
#define MAIN_BLOCKS 782                      // 3125 waves of 32 rows, +3 idle

typedef __attribute__((ext_vector_type(8)))  short short8;
typedef __attribute__((ext_vector_type(4)))  float floatx4;
typedef __attribute__((ext_vector_type(16))) float floatx16;

__device__ __forceinline__ short f2bf(float f) {
    union { __hip_bfloat16 h; short s; } u;
    u.h = __float2bfloat16(f);
    return u.s;
}

// featb: [n][64] bf16, c in [48,64) zero, row NVOX all-zero (idx<0 target).
// wtb:   frag-packed per k as 384 16B chunks: chunk = (ks*2+nt)*64 + lane,
//        element j: B[c = ks*16 + (lane>>5)*8 + j][o = nt*32 + (lane&31)],
//        matching the 32x32x16 B-operand layout (k=(lane>>5)*8+j, n=lane&31).
__global__ void __launch_bounds__(256)
prep_cvt(const float* __restrict__ feat, const float* __restrict__ wk,
         short* __restrict__ featb, short* __restrict__ wtb)
{
    int b = blockIdx.x;
    if (b < FEAT_PREP_BLKS) {
        int t = b * 256 + threadIdx.x;
        if (t < FEAT_THREADS) {
            int g = t >> 3, c8 = (t & 7) * 8;
            short8 p = (short8){0, 0, 0, 0, 0, 0, 0, 0};
            if (g < NVOX && c8 < INC) {
                const floatx4* src = (const floatx4*)(feat + g * INC + c8);
                floatx4 f0 = src[0], f1 = src[1];
                #pragma unroll
                for (int j = 0; j < 4; ++j) { p[j] = f2bf(f0[j]); p[4 + j] = f2bf(f1[j]); }
            }
            *(short8*)(featb + g * FEAT_ROW + c8) = p;
        }
    } else {
        int t = (b - FEAT_PREP_BLKS) * 256 + threadIdx.x;   // < 82944 exact
        int k = t / WTB_K, r = t % WTB_K;
        int chunk = r >> 3, j = r & 7;
        int f = chunk >> 6, lane = chunk & 63;
        int ks = f >> 1, nt = f & 1;
        int c = ks * 16 + (lane >> 5) * 8 + j;      // 0..47, no pad
        int o = nt * 32 + (lane & 31);
        wtb[t] = f2bf(wk[k * (INC_MAX * OUTC_MAX) + c * OUTC_MAX + o]);
    }
}

__global__ void __launch_bounds__(256, 3)
spconv_main(const short* __restrict__ featb, const short* __restrict__ wtb,
            const int* __restrict__ idx, float* __restrict__ out)
{
    __shared__ short Bs[4][WTB_K];   // 4 x 6KB single-k B buffers

    const int tid  = threadIdx.x;
    const int lane = tid & 63;
    const int wave = tid >> 6;
    const int l32  = lane & 31;
    const int hi   = lane >> 5;      // 0/1: which 8-k half this lane holds

    // XCD-contiguous swizzle (bijective for bid<776, identity tail)
    int bid = blockIdx.x;
    int sb  = (bid < 776) ? ((bid & 7) * 97 + (bid >> 3)) : bid;

    const int m0   = (sb * 4 + wave) * 32;     // 32 rows per wave
    const bool act = (m0 < NVOX);              // whole-wave validity (NVOX%32==0)
    const int rr   = act ? (m0 + l32) : 0;     // this lane's voxel row

    floatx16 acc[2];
    #pragma unroll
    for (int nt = 0; nt < 2; ++nt)
        #pragma unroll
        for (int r = 0; r < 16; ++r) acc[nt][r] = 0.f;

    short8 A[2][3];      // [k&1][ks] A-frag ring
    short8 bst[2][2];    // [k&1][half] B-stage ring (half 1 only for tid<128)
    int    rowg[4];      // [k&3] gathered row (idx<0 -> NVOX zero row)
    bool   va4[4];       // [k&3] wave-level tap validity (set at ldrow)
    bool   ca[2];        // [k&1] compute guard (captured at aload; va4[k&3]
                         // is clobbered by ldrow(k+4) before compute(k))

    auto ldrow = [&](int k) {
        int t0 = idx[k * NVOX + rr];
        rowg[k & 3] = (t0 < 0) ? NVOX : t0;
        va4[k & 3] = __any(t0 >= 0);
    };
    auto aload = [&](int k) {
        bool v = va4[k & 3];
        ca[k & 1] = v;
        if (v) {
            const short* p = featb + rowg[k & 3] * FEAT_ROW + hi * 8;
            A[k & 1][0] = *(const short8*)(p);
            A[k & 1][1] = *(const short8*)(p + 16);
            A[k & 1][2] = *(const short8*)(p + 32);
        }
    };
    auto bload = [&](int k) {
        bst[k & 1][0] = *(const short8*)(wtb + k * WTB_K + tid * 8);
        if (tid < 128)
            bst[k & 1][1] = *(const short8*)(wtb + k * WTB_K + 2048 + tid * 8);
    };
    auto compute = [&](int k) {
        if (!ca[k & 1]) return;
        #pragma unroll
        for (int ks = 0; ks < 3; ++ks) {
            short8 b0 = *(const short8*)&Bs[k & 3][(ks * 128 + lane) * 8];
            short8 b1 = *(const short8*)&Bs[k & 3][(ks * 128 + 64 + lane) * 8];
            acc[0] = __builtin_amdgcn_mfma_f32_32x32x16_bf16(
                A[k & 1][ks], b0, acc[0], 0, 0, 0);
            acc[1] = __builtin_amdgcn_mfma_f32_32x32x16_bf16(
                A[k & 1][ks], b1, acc[1], 0, 0, 0);
        }
    };

    // ---- prologue ----
    ldrow(0); ldrow(1); ldrow(2); ldrow(3);
    bload(0); bload(1);
    aload(0); aload(1);

    #pragma unroll
    for (int j = 0; j < 14; ++j) {
        const int kk = 2 * j;

        // commit staged B(kk), B(kk+1) regs to LDS buffers kk&3, (kk+1)&3
        *(short8*)&Bs[kk & 3][tid * 8] = bst[0][0];
        if (tid < 128) *(short8*)&Bs[kk & 3][2048 + tid * 8] = bst[0][1];
        if (kk + 1 < KOFF) {
            *(short8*)&Bs[(kk + 1) & 3][tid * 8] = bst[1][0];
            if (tid < 128) *(short8*)&Bs[(kk + 1) & 3][2048 + tid * 8] = bst[1][1];
        }
        __syncthreads();

        // stage next pair's B into regs; idx two pairs ahead
        if (kk + 2 < KOFF) bload(kk + 2);
        if (kk + 3 < KOFF) bload(kk + 3);
        if (kk + 4 < KOFF) ldrow(kk + 4);
        if (kk + 5 < KOFF) ldrow(kk + 5);

        compute(kk);
        if (kk + 2 < KOFF) aload(kk + 2);     // refills A[kk&1] after use
        if (kk + 1 < KOFF) {
            compute(kk + 1);
            if (kk + 3 < KOFF) aload(kk + 3);
        }
    }

    // ---- epilogue: D col = nt*32 + (lane&31), row = (r&3) + 8*(r>>2) + 4*hi ----
    if (act) {
        #pragma unroll
        for (int nt = 0; nt < 2; ++nt) {
            #pragma unroll
            for (int r = 0; r < 16; ++r) {
                int row = (r & 3) + 8 * (r >> 2) + 4 * hi;
                out[(m0 + row) * OUTC + nt * 32 + l32] = acc[nt][r];
            }
        }
    }
}

// Safety fallback (only if workspace were too small): plain fp32.
__global__ void __launch_bounds__(256)
spconv_fallback(const float* __restrict__ feat, const float* __restrict__ wk,
                const int* __restrict__ idx, float* __restrict__ out)
{
    int t = blockIdx.x * 256 + threadIdx.x;
    if (t >= NVOX * OUTC) return;
    int n = t >> 6, o = t & 63;
    float s = 0.f;
    for (int k = 0; k < KOFF; ++k) {
        int g = idx[k * NVOX + n];
        if (g >= 0) {
            const float* fr = feat + g * INC;
            const float* wr = wk + k * (INC_MAX * OUTC_MAX) + o;
            #pragma unroll 8
            for (int c = 0; c < INC; ++c) s += fr[c] * wr[c * OUTC_MAX];
        }
    }
    out[t] = s;
}

extern "C" void kernel_launch(void* const* d_in, const int* in_sizes, int n_in,
                              void* d_out, int out_size, void* d_ws, size_t ws_size,
                              hipStream_t stream) {
    const float* feat = (const float*)d_in[0];
    const float* wk   = (const float*)d_in[1];
    const int*   idx  = (const int*)d_in[2];
    float* out = (float*)d_out;

    if (ws_size >= WS_NEED) {
        short* featb = (short*)d_ws;
        short* wtb   = featb + FEATB_ELEMS;
        prep_cvt<<<FEAT_PREP_BLKS + WTB_PREP_BLKS, 256, 0, stream>>>(feat, wk, featb, wtb);
        spconv_main<<<MAIN_BLOCKS, 256, 0, stream>>>(featb, wtb, idx, out);
    } else {
        spconv_fallback<<<(NVOX * OUTC + 255) / 256, 256, 0, stream>>>(feat, wk, idx, out);
    }
}